// Round 8
// baseline (402.290 us; speedup 1.0000x reference)
//
#include <hip/hip_runtime.h>

// B=4, H=8, Nt=Nc=2048, D=512, E=64, scale = 1/64 folded into Wq at cast.
#define B_   4
#define H_   8
#define NSEQ 2048
#define D_   512
#define E_   64

typedef __bf16 bf16x8 __attribute__((ext_vector_type(8)));
typedef float  f32x4  __attribute__((ext_vector_type(4)));

__device__ __forceinline__ unsigned short f2b(float f) {
    __bf16 h = (__bf16)f;                     // RNE
    return __builtin_bit_cast(unsigned short, h);
}
__device__ __forceinline__ bf16x8 ld_frag(const unsigned short* p) {
    return *reinterpret_cast<const bf16x8*>(p);
}

// ---------------------------------------------------------------------------
// Cast + transpose W: [H][D][E] fp32 -> [he][d] bf16 (y=0..2); Wout (y=3).
// Wq (y=2) pre-scaled by 1/64 (exact exponent shift).
// ---------------------------------------------------------------------------
__global__ __launch_bounds__(256)
void cast_w_kernel(const float* __restrict__ Wk, const float* __restrict__ Wv,
                   const float* __restrict__ Wq, const float* __restrict__ Wo,
                   unsigned short* __restrict__ okt, unsigned short* __restrict__ ovt,
                   unsigned short* __restrict__ oqt, unsigned short* __restrict__ oo) {
    int idx = blockIdx.x * 256 + threadIdx.x;   // < 262144
    int y = blockIdx.y;
    if (y == 3) { oo[idx] = f2b(Wo[idx]); return; }
    const float* src = y == 0 ? Wk : (y == 1 ? Wv : Wq);
    unsigned short* dst = y == 0 ? okt : (y == 1 ? ovt : oqt);
    float scl = (y == 2) ? 0.015625f : 1.0f;
    int hh = idx >> 15, rem = idx & 32767, d = rem >> 6, e = rem & 63;
    dst[hh * 32768 + e * 512 + d] = f2b(src[idx] * scl);   // [(h*64+e)][d]
}

// ---------------------------------------------------------------------------
// Cast X (query/keys/values) fp32 -> bf16, layout preserved [B][N][D].
// ---------------------------------------------------------------------------
__global__ __launch_bounds__(256)
void cast_x_kernel(const float* __restrict__ xq, const float* __restrict__ xk,
                   const float* __restrict__ xv,
                   unsigned short* __restrict__ oq, unsigned short* __restrict__ ok,
                   unsigned short* __restrict__ ov) {
    const float* src = blockIdx.y == 0 ? xq : (blockIdx.y == 1 ? xk : xv);
    unsigned short* dst = blockIdx.y == 0 ? oq : (blockIdx.y == 1 ? ok : ov);
    size_t i = ((size_t)blockIdx.x * 256 + threadIdx.x) * 4;
    float4 f = *reinterpret_cast<const float4*>(src + i);
    *reinterpret_cast<ushort4*>(dst + i) =
        make_ushort4(f2b(f.x), f2b(f.y), f2b(f.z), f2b(f.w));
}

// ---------------------------------------------------------------------------
// NT-GEMM template body: C[m][n] = sum_d A[m][d] * Bt[n][d], A/Bt bf16.
// 128x128 tile, BK=64, single-buffer LDS, 2 barriers/iter, reg prefetch.
// 4 waves, wave = 32 m-rows x 128 n. 32 MFMA per wave-iter (2x frag reuse).
// ---------------------------------------------------------------------------
#define GEMM_CORE(APTR, BPTR)                                                   \
    __shared__ unsigned short Abf[128][68];                                     \
    __shared__ unsigned short Bbf[128][68];                                     \
    uint4 aU[4], bU[4];                                                         \
    _Pragma("unroll")                                                           \
    for (int i = 0; i < 4; ++i) {                                               \
        int idx = tid + i * 256;                                                \
        aU[i] = *reinterpret_cast<const uint4*>(                                \
            (APTR) + (size_t)(idx >> 3) * D_ + (idx & 7) * 8);                  \
        bU[i] = *reinterpret_cast<const uint4*>(                                \
            (BPTR) + (size_t)(idx >> 3) * D_ + (idx & 7) * 8);                  \
    }                                                                           \
    const f32x4 z = {0.f, 0.f, 0.f, 0.f};                                       \
    f32x4 acc[2][8];                                                            \
    _Pragma("unroll")                                                           \
    for (int i = 0; i < 2; ++i)                                                 \
        _Pragma("unroll")                                                       \
        for (int j = 0; j < 8; ++j) acc[i][j] = z;                              \
    for (int kt = 0; kt < 8; ++kt) {                                            \
        __syncthreads();      /* prev-iter frag reads done */                   \
        _Pragma("unroll")                                                       \
        for (int i = 0; i < 4; ++i) {                                           \
            int idx = tid + i * 256;                                            \
            *reinterpret_cast<uint4*>(&Abf[idx >> 3][(idx & 7) * 8]) = aU[i];   \
            *reinterpret_cast<uint4*>(&Bbf[idx >> 3][(idx & 7) * 8]) = bU[i];   \
        }                                                                       \
        __syncthreads();                                                        \
        if (kt < 7) {                                                           \
            int k0 = (kt + 1) * 64;                                             \
            _Pragma("unroll")                                                   \
            for (int i = 0; i < 4; ++i) {                                       \
                int idx = tid + i * 256;                                        \
                aU[i] = *reinterpret_cast<const uint4*>(                        \
                    (APTR) + (size_t)(idx >> 3) * D_ + k0 + (idx & 7) * 8);     \
                bU[i] = *reinterpret_cast<const uint4*>(                        \
                    (BPTR) + (size_t)(idx >> 3) * D_ + k0 + (idx & 7) * 8);     \
            }                                                                   \
        }                                                                       \
        _Pragma("unroll")                                                       \
        for (int kk = 0; kk < 2; ++kk) {                                        \
            bf16x8 bfr[8];                                                      \
            _Pragma("unroll")                                                   \
            for (int nt = 0; nt < 8; ++nt)                                      \
                bfr[nt] = ld_frag(&Bbf[nt * 16 + l16][kk * 32 + quad * 8]);     \
            _Pragma("unroll")                                                   \
            for (int mt = 0; mt < 2; ++mt) {                                    \
                bf16x8 af = ld_frag(&Abf[wave * 32 + mt * 16 + l16]             \
                                        [kk * 32 + quad * 8]);                  \
                _Pragma("unroll")                                               \
                for (int nt = 0; nt < 8; ++nt)                                  \
                    acc[mt][nt] = __builtin_amdgcn_mfma_f32_16x16x32_bf16(      \
                        af, bfr[nt], acc[mt][nt], 0, 0, 0);                     \
            }                                                                   \
        }                                                                       \
    }                                                                           \
    __syncthreads();   /* frag reads done; LDS reusable as epilogue staging */

// ---------------------------------------------------------------------------
// Projection: C[m][he] from xb (bf16) and Wt[he][d]. which: 0=Q 1=K 2=V.
// Q/K: natural [m][he]; V: transposed vtb[b][h][e][n].
// ---------------------------------------------------------------------------
__global__ __launch_bounds__(256, 3)
void proj_gemm(const unsigned short* __restrict__ xq,
               const unsigned short* __restrict__ xk,
               const unsigned short* __restrict__ xv,
               const unsigned short* __restrict__ wqt,
               const unsigned short* __restrict__ wkt,
               const unsigned short* __restrict__ wvt,
               unsigned short* __restrict__ qb, unsigned short* __restrict__ kb,
               unsigned short* __restrict__ vtb) {
    const int m0  = blockIdx.x * 128;
    const int no0 = blockIdx.y * 128;
    const int which = blockIdx.z;
    const int tid = threadIdx.x;
    const int wave = tid >> 6, lane = tid & 63;
    const int quad = lane >> 4, l16 = lane & 15;

    const unsigned short* X = which == 0 ? xq : (which == 1 ? xk : xv);
    const unsigned short* W = which == 0 ? wqt : (which == 1 ? wkt : wvt);
    const unsigned short* Ap = X + (size_t)m0 * D_;
    const unsigned short* Bp = W + (size_t)no0 * D_;

    GEMM_CORE(Ap, Bp)

    unsigned short (*Os)[136] = reinterpret_cast<unsigned short(*)[136]>(&Abf[0][0]);
    if (which != 2) {
        #pragma unroll
        for (int mt = 0; mt < 2; ++mt)
            #pragma unroll
            for (int nt = 0; nt < 8; ++nt)
                #pragma unroll
                for (int r = 0; r < 4; ++r)
                    Os[wave * 32 + mt * 16 + quad * 4 + r][nt * 16 + l16] =
                        f2b(acc[mt][nt][r]);
        __syncthreads();
        unsigned short* Y = (which == 0 ? qb : kb);
        #pragma unroll
        for (int i = 0; i < 8; ++i) {
            int idx = tid + i * 256;
            int row = idx >> 4, seg = idx & 15;
            *reinterpret_cast<uint4*>(Y + (size_t)(m0 + row) * D_ + no0 + seg * 8) =
                *reinterpret_cast<const uint4*>(&Os[row][seg * 8]);
        }
    } else {
        #pragma unroll
        for (int mt = 0; mt < 2; ++mt)
            #pragma unroll
            for (int nt = 0; nt < 8; ++nt) {
                ushort4 o = make_ushort4(f2b(acc[mt][nt][0]), f2b(acc[mt][nt][1]),
                                         f2b(acc[mt][nt][2]), f2b(acc[mt][nt][3]));
                *reinterpret_cast<ushort4*>(
                    &Os[nt * 16 + l16][wave * 32 + mt * 16 + quad * 4]) = o;
            }
        __syncthreads();
        const int b = m0 >> 11, nloc = m0 & 2047;
        #pragma unroll
        for (int i = 0; i < 8; ++i) {
            int idx = tid + i * 256;
            int lhe = idx >> 4, seg = idx & 15;
            int ghe = no0 + lhe;                 // h = ghe>>6, e = ghe&63
            *reinterpret_cast<uint4*>(
                vtb + ((size_t)(b * H_ + (ghe >> 6)) * E_ + (ghe & 63)) * NSEQ +
                nloc + seg * 8) =
                *reinterpret_cast<const uint4*>(&Os[lhe][seg * 8]);
        }
    }
}

// ---------------------------------------------------------------------------
// Output NT-GEMM: Out[m][o] = sum_d aob[m][d] * Wout[o][d]. fp32 out, direct.
// ---------------------------------------------------------------------------
__global__ __launch_bounds__(256, 3)
void out_gemm(const unsigned short* __restrict__ A,
              const unsigned short* __restrict__ Wo,
              float* __restrict__ Out) {
    const int m0  = blockIdx.x * 128;
    const int no0 = blockIdx.y * 128;
    const int tid = threadIdx.x;
    const int wave = tid >> 6, lane = tid & 63;
    const int quad = lane >> 4, l16 = lane & 15;

    const unsigned short* Ap = A + (size_t)m0 * D_;
    const unsigned short* Bp = Wo + (size_t)no0 * D_;

    GEMM_CORE(Ap, Bp)

    #pragma unroll
    for (int mt = 0; mt < 2; ++mt)
        #pragma unroll
        for (int nt = 0; nt < 8; ++nt)
            #pragma unroll
            for (int r = 0; r < 4; ++r)
                Out[(size_t)(m0 + wave * 32 + mt * 16 + quad * 4 + r) * D_ +
                    no0 + nt * 16 + l16] = acc[mt][nt][r];
}

// ---------------------------------------------------------------------------
// Flash attention, transposed-S. Block = 128 Q-rows (4 waves x 32), 64-key
// dbuf tiles, 1 barrier/iter, commit+prefetch at iteration TOP (max vmcnt
// slack). No explicit lgkm fence: same-wave DS ops are pipe-ordered.
//   St = K·Q^T (A = K rows, B = Q regs, 2x reuse across ng)
//   P  = exp(St) -> wave-private LDS rows (m=0 softmax, deferred l)
//   O^T = V^T·P^T (A = V^T rows, 2x reuse across ng)
// 32 MFMA per wave-iter vs 16 ds_read_b128.
// ---------------------------------------------------------------------------
__global__ __launch_bounds__(256, 3)
void attn_kernel(const unsigned short* __restrict__ qbp,
                 const unsigned short* __restrict__ kbp,
                 const unsigned short* __restrict__ vtbp,
                 unsigned short* __restrict__ aob) {
    const int L = blockIdx.x;
    const int bh = L & 31, qt = L >> 5;      // L%8 pattern -> XCD K/V affinity
    const int b = bh >> 3, h = bh & 7;
    const int n0 = qt * 128;
    const int tid = threadIdx.x;
    const int wave = tid >> 6, lane = tid & 63;
    const int quad = lane >> 4, l16 = lane & 15;

    __shared__ unsigned short Ks[2][64][68];   // 17.4 KB
    __shared__ unsigned short Vs[2][64][68];   // 17.4 KB
    __shared__ unsigned short Ps[128][68];     // 17.4 KB (wave-private rows)

    const unsigned short* kbase = kbp + (size_t)(b * NSEQ) * D_ + h * 64;
    const unsigned short* vbase = vtbp + (size_t)(b * H_ + h) * E_ * NSEQ;

    // Q B-frags, loaded once; wave owns qrows n0+wave*32 .. +32 (2 ng groups)
    bf16x8 qf[2][2];   // [kk][ng]
    #pragma unroll
    for (int ng = 0; ng < 2; ++ng)
        #pragma unroll
        for (int kk = 0; kk < 2; ++kk)
            qf[kk][ng] = ld_frag(
                qbp + (size_t)(b * NSEQ + n0 + wave * 32 + ng * 16 + l16) * D_ +
                h * 64 + kk * 32 + quad * 8);

    uint4 kr[2], vr[2];
    #define ATTN_LOAD(j)                                                       \
        {   _Pragma("unroll")                                                  \
            for (int i = 0; i < 2; ++i) {                                      \
                int idx = tid + i * 256;                                       \
                kr[i] = *reinterpret_cast<const uint4*>(                       \
                    kbase + (size_t)((j) * 64 + (idx >> 3)) * D_ + (idx & 7) * 8); \
                vr[i] = *reinterpret_cast<const uint4*>(                       \
                    vbase + (size_t)(idx >> 3) * NSEQ + (j) * 64 + (idx & 7) * 8); \
            } }
    #define ATTN_COMMIT(buf)                                                   \
        {   _Pragma("unroll")                                                  \
            for (int i = 0; i < 2; ++i) {                                      \
                int idx = tid + i * 256;                                       \
                *reinterpret_cast<uint4*>(&Ks[buf][idx >> 3][(idx & 7) * 8]) = kr[i]; \
                *reinterpret_cast<uint4*>(&Vs[buf][idx >> 3][(idx & 7) * 8]) = vr[i]; \
            } }

    ATTN_LOAD(0)
    ATTN_COMMIT(0)
    ATTN_LOAD(1)
    __syncthreads();

    const f32x4 z = {0.f, 0.f, 0.f, 0.f};
    f32x4 oacc[4][2];                        // [eg][ng]
    #pragma unroll
    for (int i = 0; i < 4; ++i) { oacc[i][0] = z; oacc[i][1] = z; }
    float lacc[2] = {0.f, 0.f};

    for (int j = 0; j < NSEQ / 64; ++j) {
        const int cur = j & 1;

        // commit tile j+1 (regs loaded at iter j-1); prefetch tile j+2
        if (j < NSEQ / 64 - 1) {
            ATTN_COMMIT(1 - cur)
            if (j + 2 < NSEQ / 64) ATTN_LOAD(j + 2)
        }

        // St = K·Q^T : C[key = mg*16+quad*4+r][qrow = l16 (per ng)]
        f32x4 sacc[4][2];
        #pragma unroll
        for (int mg = 0; mg < 4; ++mg) { sacc[mg][0] = z; sacc[mg][1] = z; }
        #pragma unroll
        for (int kk = 0; kk < 2; ++kk)
            #pragma unroll
            for (int mg = 0; mg < 4; ++mg) {
                bf16x8 af = ld_frag(&Ks[cur][mg * 16 + l16][kk * 32 + quad * 8]);
                sacc[mg][0] = __builtin_amdgcn_mfma_f32_16x16x32_bf16(
                    af, qf[kk][0], sacc[mg][0], 0, 0, 0);
                sacc[mg][1] = __builtin_amdgcn_mfma_f32_16x16x32_bf16(
                    af, qf[kk][1], sacc[mg][1], 0, 0, 0);
            }

        // exp (m=0), commit P as ushort4 (4 consecutive keys), defer l
        #pragma unroll
        for (int ng = 0; ng < 2; ++ng) {
            float ls = 0.f;
            #pragma unroll
            for (int mg = 0; mg < 4; ++mg) {
                float p0 = __expf(sacc[mg][ng][0]);
                float p1 = __expf(sacc[mg][ng][1]);
                float p2 = __expf(sacc[mg][ng][2]);
                float p3 = __expf(sacc[mg][ng][3]);
                ls += (p0 + p1) + (p2 + p3);
                ushort4 pk = make_ushort4(f2b(p0), f2b(p1), f2b(p2), f2b(p3));
                *reinterpret_cast<ushort4*>(
                    &Ps[wave * 32 + ng * 16 + l16][mg * 16 + quad * 4]) = pk;
            }
            lacc[ng] += ls;
        }
        // (no fence: same-wave DS ops are in-order; compiler keeps program
        //  order on may-alias Ps accesses and can overlap Vs reads freely)

        // O^T += V^T·P^T
        #pragma unroll
        for (int kkv = 0; kkv < 2; ++kkv) {
            bf16x8 pf0 = ld_frag(&Ps[wave * 32 + l16][kkv * 32 + quad * 8]);
            bf16x8 pf1 = ld_frag(&Ps[wave * 32 + 16 + l16][kkv * 32 + quad * 8]);
            #pragma unroll
            for (int eg = 0; eg < 4; ++eg) {
                bf16x8 af = ld_frag(&Vs[cur][eg * 16 + l16][kkv * 32 + quad * 8]);
                oacc[eg][0] = __builtin_amdgcn_mfma_f32_16x16x32_bf16(
                    af, pf0, oacc[eg][0], 0, 0, 0);
                oacc[eg][1] = __builtin_amdgcn_mfma_f32_16x16x32_bf16(
                    af, pf1, oacc[eg][1], 0, 0, 0);
            }
        }
        __syncthreads();                        // single barrier per iter
    }

    // epilogue: reduce l across quads, scale, store (4 consecutive e = ushort4)
    #pragma unroll
    for (int ng = 0; ng < 2; ++ng) {
        float s = lacc[ng];
        s += __shfl_xor(s, 16);
        s += __shfl_xor(s, 32);
        float li = 1.0f / s;
        unsigned short* op =
            aob + (size_t)(b * NSEQ + n0 + wave * 32 + ng * 16 + l16) * D_ +
            h * 64 + quad * 4;
        #pragma unroll
        for (int eg = 0; eg < 4; ++eg) {
            ushort4 o = make_ushort4(f2b(oacc[eg][ng][0] * li),
                                     f2b(oacc[eg][ng][1] * li),
                                     f2b(oacc[eg][ng][2] * li),
                                     f2b(oacc[eg][ng][3] * li));
            *reinterpret_cast<ushort4*>(op + eg * 16) = o;
        }
    }
    #undef ATTN_LOAD
    #undef ATTN_COMMIT
}

// ---------------------------------------------------------------------------
extern "C" void kernel_launch(void* const* d_in, const int* in_sizes, int n_in,
                              void* d_out, int out_size, void* d_ws, size_t ws_size,
                              hipStream_t stream) {
    const float* keys   = (const float*)d_in[0];
    const float* values = (const float*)d_in[1];
    const float* query  = (const float*)d_in[2];
    const float* Wk     = (const float*)d_in[3];
    const float* Wv     = (const float*)d_in[4];
    const float* Wq     = (const float*)d_in[5];
    const float* Wout   = (const float*)d_in[6];
    float* out = (float*)d_out;

    unsigned short* ws16 = (unsigned short*)d_ws;
    const size_t XN = (size_t)B_ * NSEQ * D_;      // 4,194,304
    const size_t WN = (size_t)H_ * D_ * E_;        // 262,144
    unsigned short* wkt = ws16;                    // [he][d]
    unsigned short* wvt = wkt + WN;
    unsigned short* wqt = wvt + WN;                // pre-scaled by 1/64
    unsigned short* wob = wqt + WN;
    unsigned short* xq  = wob + WN;                // bf16 copies of inputs
    unsigned short* xk  = xq + XN;
    unsigned short* xv  = xk + XN;
    unsigned short* qb  = xv + XN;                 // [8192][512], col=h*64+e
    unsigned short* kb  = qb + XN;                 // [8192][512]
    unsigned short* vtb = kb + XN;                 // [b][h][e][n]
    unsigned short* aob = vtb + XN;                // [8192][512] head-concat
    // total 7*XN + 4*WN = 60.8 MB

    cast_w_kernel<<<dim3(1024, 4), 256, 0, stream>>>(Wk, Wv, Wq, Wout,
                                                     wkt, wvt, wqt, wob);
    cast_x_kernel<<<dim3(4096, 3), 256, 0, stream>>>(query, keys, values,
                                                     xq, xk, xv);

    proj_gemm<<<dim3(64, 4, 3), 256, 0, stream>>>(
        xq, xk, xv, wqt, wkt, wvt, qb, kb, vtb);

    attn_kernel<<<dim3(512), 256, 0, stream>>>(qb, kb, vtb, aob);

    out_gemm<<<dim3(64, 4), 256, 0, stream>>>(aob, wob, out);
}